// Round 3
// baseline (249.295 us; speedup 1.0000x reference)
//
#include <hip/hip_runtime.h>
#include <hip/hip_cooperative_groups.h>

namespace cg = cooperative_groups;

#define NXD 128
#define NYD 128
#define SRC_XD 64
#define SRC_YD 64
#define T_STEPSD 256
#define BATCHD 8
#define N_PROBESD 4

typedef float v2f __attribute__((ext_vector_type(2)));

// DPP cross-lane single shifts across the full wave64.
// WAVE_SHR1 (0x138): lane i <- lane i-1, lane0 -> 0 (bound_ctrl)
// WAVE_SHL1 (0x130): lane i <- lane i+1, lane63 -> 0
// Zero-fill matches the conv 'SAME' zero padding at col -1 / col 128.
__device__ __forceinline__ float dpp_from_lower(float v) {
    return __int_as_float(__builtin_amdgcn_update_dpp(0, __float_as_int(v), 0x138, 0xF, 0xF, true));
}
__device__ __forceinline__ float dpp_from_upper(float v) {
    return __int_as_float(__builtin_amdgcn_update_dpp(0, __float_as_int(v), 0x130, 0xF, 0xF, true));
}

// One row update (2 cells). Plain C v2f ops: round-2 proved the compiler
// already packs these into v_pk_add_f32/v_pk_fma_f32 and schedules better
// than pinned inline asm.
//   lap = up + dn + {lf + Y.y, Y.x + rt} - 4*Y ;  Z = K*lap + (C2 + K2*Z)
#define ROW(up, dn, Yr, Zr, Kr) { \
    const float lf = dpp_from_lower((Yr).y); \
    const float rt = dpp_from_upper((Yr).x); \
    v2f cross; cross.x = lf + (Yr).y; cross.y = (Yr).x + rt; \
    const v2f lap = (up) + (dn) + cross - 4.0f * (Yr); \
    (Zr) = (Kr) * lap + (C2v + K2v * (Zr)); \
}

// Wave-uniform 8-way register select (ro is an SGPR via readfirstlane ->
// scalar branch tree, not a cndmask chain).
#define PSEL(ro, Z, pv) switch (ro) { \
    case 0:  pv = (Z##0);  break; \
    case 1:  pv = (Z##1);  break; \
    case 2:  pv = (Z##2);  break; \
    case 3:  pv = (Z##3);  break; \
    case 4:  pv = (Z##4);  break; \
    case 5:  pv = (Z##5);  break; \
    case 6:  pv = (Z##6);  break; \
    default: pv = (Z##7);  break; \
}

// One time step: Y = current (read-only), Z = previous, overwritten with new.
// Rows 1..6 first (independent of the halo ds_reads issued at top, hiding
// their ~120 cy latency), then rows 0 and 7, source add, halo publish,
// probe accumulation, barrier.
// NOTE: source add hardcodes (Z##0).x -- valid because SRC_XD & 7 == 0 and
// SRC_YD is even, and it happens BEFORE the halo publish of Z##0.
#define STEP(Y, Z, tt, xsv) { \
    const int buf_ = (tt) & 1, nb_ = buf_ ^ 1; \
    const v2f ra = *(const v2f*)&haloBot[buf_][wa][colb]; \
    const v2f rb = *(const v2f*)&haloTop[buf_][wb][colb]; \
    ROW(Y##0,  Y##2,  Y##1,  Z##1,  k1) \
    ROW(Y##1,  Y##3,  Y##2,  Z##2,  k2) \
    ROW(Y##2,  Y##4,  Y##3,  Z##3,  k3) \
    ROW(Y##3,  Y##5,  Y##4,  Z##4,  k4) \
    ROW(Y##4,  Y##6,  Y##5,  Z##5,  k5) \
    ROW(Y##5,  Y##7,  Y##6,  Z##6,  k6) \
    ROW(ra,    Y##1,  Y##0,  Z##0,  k0) \
    ROW(Y##6,  rb,    Y##7,  Z##7,  k7) \
    if (has_src) { if (own_src) (Z##0).x += (xsv); } \
    *(v2f*)&haloTop[nb_][w][colb] = (Z##0); \
    *(v2f*)&haloBot[nb_][w][colb] = (Z##7); \
    if (whas0) { v2f pv; PSEL(pro0s, Z, pv) accv0 += pv * pv; } \
    if (whas1) { v2f pv; PSEL(pro1s, Z, pv) accv1 += pv * pv; } \
    if (whas2) { v2f pv; PSEL(pro2s, Z, pv) accv2 += pv * pv; } \
    if (whas3) { v2f pv; PSEL(pro3s, Z, pv) accv3 += pv * pv; } \
    __syncthreads(); \
}

// 1024 threads = 16 waves x 8 rows = 4 waves/EU, 1 block/CU.
// Rationale: round-2 showed the kernel is per-wave latency-bound (halving
// instruction count changed nothing). Same total issue per SIMD, but each
// wave's chain halves and 4-way interleave hides VALU/DPP/LDS latency.
// State/wave: Y 16 + Z 16 + K 16 + acc 8 + misc ~20 = ~76 VGPR < 128 cap.
__global__ __launch_bounds__(1024, 4) void wave_sim(
        const float* __restrict__ x,        // (T,B)
        const float* __restrict__ c,        // (NX,NY)
        const int*   __restrict__ probes,   // (4,2) int
        float* __restrict__ partial,        // (B,4) workspace
        float* __restrict__ out)            // (4)
{
    __shared__ float haloTop[2][17][NYD];   // [16] = permanent zero ghost row
    __shared__ float haloBot[2][17][NYD];
    __shared__ float xs[T_STEPSD];

    const int tid = threadIdx.x;
    const int w = tid >> 6;       // wave 0..15, owns rows 8w..8w+7
    const int l = tid & 63;       // lane, owns cols 2l, 2l+1
    const int b = blockIdx.x;

    const float dt = 0.5f, bdamp = 0.005f;
    const float denom = 1.0f / (dt * dt) + 0.5f * bdamp / dt;  // 4.005
    const float inv_denom = 1.0f / denom;
    const float C2 = 2.0f * inv_denom;
    const float K2 = (-1.0f - dt * bdamp) * inv_denom;
    const float KL = dt * dt * inv_denom;
    v2f C2v; C2v.x = C2; C2v.y = C2;
    v2f K2v; K2v.x = K2; K2v.y = K2;

    for (int i = tid; i < 2 * 17 * NYD; i += 1024) {
        ((float*)haloTop)[i] = 0.0f;
        ((float*)haloBot)[i] = 0.0f;
    }
    if (tid < T_STEPSD) xs[tid] = x[tid * BATCHD + b];

    const int rowbase = w * 8;
    const int colb = 2 * l;
#define LOADK(r) \
    v2f k##r; { \
        const v2f cc = *(const v2f*)&c[(rowbase + r) * NYD + colb]; \
        k##r = KL * cc * cc; \
    }
    LOADK(0) LOADK(1) LOADK(2) LOADK(3) LOADK(4) LOADK(5) LOADK(6) LOADK(7)
#undef LOADK

    v2f zz; zz.x = 0.0f; zz.y = 0.0f;
    v2f a0 = zz, a1 = zz, a2 = zz, a3 = zz, a4 = zz, a5 = zz, a6 = zz, a7 = zz;
    v2f b0 = zz, b1 = zz, b2 = zz, b3 = zz, b4 = zz, b5 = zz, b6 = zz, b7 = zz;

    // probes: coordinates are wave-uniform (same global load in every lane)
    const int px0 = probes[0] & 127, py0 = probes[1] & 127;
    const int px1 = probes[2] & 127, py1 = probes[3] & 127;
    const int px2 = probes[4] & 127, py2 = probes[5] & 127;
    const int px3 = probes[6] & 127, py3 = probes[7] & 127;
    const bool own0 = ((px0 >> 3) == w) && ((py0 >> 1) == l);
    const bool own1 = ((px1 >> 3) == w) && ((py1 >> 1) == l);
    const bool own2 = ((px2 >> 3) == w) && ((py2 >> 1) == l);
    const bool own3 = ((px3 >> 3) == w) && ((py3 >> 1) == l);
    const bool whas0 = __ballot(own0) != 0ULL;   // uniform: this wave holds probe 0
    const bool whas1 = __ballot(own1) != 0ULL;
    const bool whas2 = __ballot(own2) != 0ULL;
    const bool whas3 = __ballot(own3) != 0ULL;
    const int pro0s = __builtin_amdgcn_readfirstlane(px0 & 7);
    const int pro1s = __builtin_amdgcn_readfirstlane(px1 & 7);
    const int pro2s = __builtin_amdgcn_readfirstlane(px2 & 7);
    const int pro3s = __builtin_amdgcn_readfirstlane(px3 & 7);
    const int pel0 = py0 & 1, pel1 = py1 & 1, pel2 = py2 & 1, pel3 = py3 & 1;
    v2f accv0 = zz, accv1 = zz, accv2 = zz, accv3 = zz;

    const bool has_src = (w == (SRC_XD >> 3));            // wave 8, local row 0
    const bool own_src = has_src && (l == (SRC_YD >> 1)); // SRC_YD even -> .x

    const int wa = (w == 0) ? 16 : w - 1;    // 16 = zero ghost row
    const int wb = (w == 15) ? 16 : w + 1;

    __syncthreads();

#pragma unroll 1
    for (int t = 0; t < T_STEPSD; t += 2) {
        // one ds_read_b64 covers both steps' source values
        const v2f xp = *(const v2f*)&xs[t];
        STEP(a, b, t, xp.x)
        STEP(b, a, t + 1, xp.y)
    }

    if (own0) partial[b * N_PROBESD + 0] = pel0 ? accv0.y : accv0.x;
    if (own1) partial[b * N_PROBESD + 1] = pel1 ? accv1.y : accv1.x;
    if (own2) partial[b * N_PROBESD + 2] = pel2 ? accv2.y : accv2.x;
    if (own3) partial[b * N_PROBESD + 3] = pel3 ? accv3.y : accv3.x;

    // Fused reduction: kills the ~50 us second-launch overhead seen in every
    // round. grid.sync() orders the partial[] writes device-wide (plus an
    // explicit fence for cross-XCD safety).
    __threadfence();
    cg::this_grid().sync();

    if (b == 0 && tid < N_PROBESD) {
        float s = 0.0f, tot = 0.0f;
        for (int bb = 0; bb < BATCHD; ++bb) s += partial[bb * N_PROBESD + tid];
        for (int i = 0; i < BATCHD * N_PROBESD; ++i) tot += partial[i];
        out[tid] = s / tot;
    }
}

extern "C" void kernel_launch(void* const* d_in, const int* in_sizes, int n_in,
                              void* d_out, int out_size, void* d_ws, size_t ws_size,
                              hipStream_t stream) {
    const float* x      = (const float*)d_in[0];
    const float* c      = (const float*)d_in[1];
    const int*   probes = (const int*)d_in[2];
    float* out = (float*)d_out;
    float* partial = (float*)d_ws;

    void* args[] = { (void*)&x, (void*)&c, (void*)&probes, (void*)&partial, (void*)&out };
    hipLaunchCooperativeKernel((void*)wave_sim, dim3(BATCHD), dim3(1024), args, 0, stream);
}

// Round 4
// 199.449 us; speedup vs baseline: 1.2499x; 1.2499x over previous
//
#include <hip/hip_runtime.h>

#define NXD 128
#define NYD 128
#define SRC_XD 64
#define SRC_YD 64
#define T_STEPSD 256
#define BATCHD 8
#define N_PROBESD 4

typedef float v2f __attribute__((ext_vector_type(2)));

// DPP cross-lane single shifts across the full wave64.
// WAVE_SHR1 (0x138): lane i <- lane i-1, lane0 -> 0 (bound_ctrl)
// WAVE_SHL1 (0x130): lane i <- lane i+1, lane63 -> 0
// Zero-fill matches the conv 'SAME' zero padding at col -1 / col 128.
__device__ __forceinline__ float dpp_from_lower(float v) {
    return __int_as_float(__builtin_amdgcn_update_dpp(0, __float_as_int(v), 0x138, 0xF, 0xF, true));
}
__device__ __forceinline__ float dpp_from_upper(float v) {
    return __int_as_float(__builtin_amdgcn_update_dpp(0, __float_as_int(v), 0x130, 0xF, 0xF, true));
}

// One row update (2 cells). Plain C v2f ops: the compiler packs these into
// v_pk_add_f32/v_pk_fma_f32 (pk = 4 cy/wave64; a ROW ~28 cy of VALU pipe).
//   lap = up + dn + {lf + Y.y, Y.x + rt} - 4*Y ;  Z = K*lap + (C2 + K2*Z)
#define ROW(up, dn, Yr, Zr, Kr) { \
    const float lf = dpp_from_lower((Yr).y); \
    const float rt = dpp_from_upper((Yr).x); \
    v2f cross; cross.x = lf + (Yr).y; cross.y = (Yr).x + rt; \
    const v2f lap = (up) + (dn) + cross - 4.0f * (Yr); \
    (Zr) = (Kr) * lap + (C2v + K2v * (Zr)); \
}

// Wave-uniform 8-way register select -- used ONCE after the time loop
// (per-step branchy selection was on the pre-barrier critical path).
#define PSEL(ro, Z, pv) switch (ro) { \
    case 0:  pv = (Z##0);  break; \
    case 1:  pv = (Z##1);  break; \
    case 2:  pv = (Z##2);  break; \
    case 3:  pv = (Z##3);  break; \
    case 4:  pv = (Z##4);  break; \
    case 5:  pv = (Z##5);  break; \
    case 6:  pv = (Z##6);  break; \
    default: pv = (Z##7);  break; \
}

// One time step: Y = current (read-only), Z = previous, overwritten with new.
// Order: issue halo ds_reads; 3 interior ROWs cover their ~120 cy latency;
// rows 0 and 7 + source add + halo ds_writes issue MID-step so the
// write-drain (s_waitcnt lgkmcnt(0) before s_barrier) is covered by rows
// 1,5,6 and the branch-free acc8 fmas. Probe accumulation is unconditional
// over all 8 rows in owning waves (no scalar-branch trees per step).
// NOTE: source add hardcodes (Z##0).x -- valid because SRC_XD & 7 == 0 and
// SRC_YD is even, and it happens BEFORE the halo publish of Z##0.
#define STEP(Y, Z, tt, xsv) { \
    const int buf_ = (tt) & 1, nb_ = buf_ ^ 1; \
    const v2f ra = *(const v2f*)&haloBot[buf_][wa][colb]; \
    const v2f rb = *(const v2f*)&haloTop[buf_][wb][colb]; \
    ROW(Y##1,  Y##3,  Y##2,  Z##2,  k2) \
    ROW(Y##2,  Y##4,  Y##3,  Z##3,  k3) \
    ROW(Y##3,  Y##5,  Y##4,  Z##4,  k4) \
    ROW(ra,    Y##1,  Y##0,  Z##0,  k0) \
    if (has_src) { if (own_src) (Z##0).x += (xsv); } \
    *(v2f*)&haloTop[nb_][w][colb] = (Z##0); \
    ROW(Y##6,  rb,    Y##7,  Z##7,  k7) \
    *(v2f*)&haloBot[nb_][w][colb] = (Z##7); \
    ROW(Y##0,  Y##2,  Y##1,  Z##1,  k1) \
    ROW(Y##4,  Y##6,  Y##5,  Z##5,  k5) \
    ROW(Y##5,  Y##7,  Y##6,  Z##6,  k6) \
    if (anyprobe) { \
        acc8_0 += (Z##0) * (Z##0); acc8_1 += (Z##1) * (Z##1); \
        acc8_2 += (Z##2) * (Z##2); acc8_3 += (Z##3) * (Z##3); \
        acc8_4 += (Z##4) * (Z##4); acc8_5 += (Z##5) * (Z##5); \
        acc8_6 += (Z##6) * (Z##6); acc8_7 += (Z##7) * (Z##7); \
    } \
    __syncthreads(); \
}

// 1024 threads = 16 waves x 8 rows = 4 waves/EU, 1 block/CU.
// State/wave: Y 16 + Z 16 + K 16 + acc8 16 + misc ~20 = ~84 VGPR < 128 cap.
__global__ __launch_bounds__(1024, 4) void wave_sim(
        const float* __restrict__ x,        // (T,B)
        const float* __restrict__ c,        // (NX,NY)
        const int*   __restrict__ probes,   // (4,2) int
        float* __restrict__ partial)        // (B,4) workspace
{
    __shared__ float haloTop[2][17][NYD];   // [16] = permanent zero ghost row
    __shared__ float haloBot[2][17][NYD];
    __shared__ float xs[T_STEPSD];

    const int tid = threadIdx.x;
    const int w = tid >> 6;       // wave 0..15, owns rows 8w..8w+7
    const int l = tid & 63;       // lane, owns cols 2l, 2l+1
    const int b = blockIdx.x;

    const float dt = 0.5f, bdamp = 0.005f;
    const float denom = 1.0f / (dt * dt) + 0.5f * bdamp / dt;  // 4.005
    const float inv_denom = 1.0f / denom;
    const float C2 = 2.0f * inv_denom;
    const float K2 = (-1.0f - dt * bdamp) * inv_denom;
    const float KL = dt * dt * inv_denom;
    v2f C2v; C2v.x = C2; C2v.y = C2;
    v2f K2v; K2v.x = K2; K2v.y = K2;

    for (int i = tid; i < 2 * 17 * NYD; i += 1024) {
        ((float*)haloTop)[i] = 0.0f;
        ((float*)haloBot)[i] = 0.0f;
    }
    if (tid < T_STEPSD) xs[tid] = x[tid * BATCHD + b];

    const int rowbase = w * 8;
    const int colb = 2 * l;
#define LOADK(r) \
    v2f k##r; { \
        const v2f cc = *(const v2f*)&c[(rowbase + r) * NYD + colb]; \
        k##r = KL * cc * cc; \
    }
    LOADK(0) LOADK(1) LOADK(2) LOADK(3) LOADK(4) LOADK(5) LOADK(6) LOADK(7)
#undef LOADK

    v2f zz; zz.x = 0.0f; zz.y = 0.0f;
    v2f a0 = zz, a1 = zz, a2 = zz, a3 = zz, a4 = zz, a5 = zz, a6 = zz, a7 = zz;
    v2f b0 = zz, b1 = zz, b2 = zz, b3 = zz, b4 = zz, b5 = zz, b6 = zz, b7 = zz;
    v2f acc8_0 = zz, acc8_1 = zz, acc8_2 = zz, acc8_3 = zz,
        acc8_4 = zz, acc8_5 = zz, acc8_6 = zz, acc8_7 = zz;

    // probes: coordinates are wave-uniform (same global load in every lane)
    const int px0 = probes[0] & 127, py0 = probes[1] & 127;
    const int px1 = probes[2] & 127, py1 = probes[3] & 127;
    const int px2 = probes[4] & 127, py2 = probes[5] & 127;
    const int px3 = probes[6] & 127, py3 = probes[7] & 127;
    const bool own0 = ((px0 >> 3) == w) && ((py0 >> 1) == l);
    const bool own1 = ((px1 >> 3) == w) && ((py1 >> 1) == l);
    const bool own2 = ((px2 >> 3) == w) && ((py2 >> 1) == l);
    const bool own3 = ((px3 >> 3) == w) && ((py3 >> 1) == l);
    // wave-uniform: does THIS wave hold any probe row?
    const bool anyprobe = __ballot(own0 | own1 | own2 | own3) != 0ULL;
    const int pro0s = __builtin_amdgcn_readfirstlane(px0 & 7);
    const int pro1s = __builtin_amdgcn_readfirstlane(px1 & 7);
    const int pro2s = __builtin_amdgcn_readfirstlane(px2 & 7);
    const int pro3s = __builtin_amdgcn_readfirstlane(px3 & 7);
    const int pel0 = py0 & 1, pel1 = py1 & 1, pel2 = py2 & 1, pel3 = py3 & 1;

    const bool has_src = (w == (SRC_XD >> 3));            // wave 8, local row 0
    const bool own_src = has_src && (l == (SRC_YD >> 1)); // SRC_YD even -> .x

    const int wa = (w == 0) ? 16 : w - 1;    // 16 = zero ghost row
    const int wb = (w == 15) ? 16 : w + 1;

    __syncthreads();

#pragma unroll 1
    for (int t = 0; t < T_STEPSD; t += 2) {
        // one ds_read_b64 covers both steps' source values
        const v2f xp = *(const v2f*)&xs[t];
        STEP(a, b, t, xp.x)
        STEP(b, a, t + 1, xp.y)
    }

    // One-time probe selection from the 8 per-row accumulators. The selected
    // accumulator saw exactly the same per-step add sequence as the old
    // per-step-selected accumulator -> bit-identical.
    if (own0) { v2f pv; PSEL(pro0s, acc8_, pv) partial[b * N_PROBESD + 0] = pel0 ? pv.y : pv.x; }
    if (own1) { v2f pv; PSEL(pro1s, acc8_, pv) partial[b * N_PROBESD + 1] = pel1 ? pv.y : pv.x; }
    if (own2) { v2f pv; PSEL(pro2s, acc8_, pv) partial[b * N_PROBESD + 2] = pel2 ? pv.y : pv.x; }
    if (own3) { v2f pv; PSEL(pro3s, acc8_, pv) partial[b * N_PROBESD + 3] = pel3 ? pv.y : pv.x; }
}

__global__ void reduce_k(const float* __restrict__ partial, float* __restrict__ out) {
    const int p = threadIdx.x;
    if (p < N_PROBESD) {
        float s = 0.0f, tot = 0.0f;
        for (int bb = 0; bb < BATCHD; ++bb) s += partial[bb * N_PROBESD + p];
        for (int i = 0; i < BATCHD * N_PROBESD; ++i) tot += partial[i];
        out[p] = s / tot;
    }
}

extern "C" void kernel_launch(void* const* d_in, const int* in_sizes, int n_in,
                              void* d_out, int out_size, void* d_ws, size_t ws_size,
                              hipStream_t stream) {
    const float* x      = (const float*)d_in[0];
    const float* c      = (const float*)d_in[1];
    const int*   probes = (const int*)d_in[2];
    float* out = (float*)d_out;
    float* partial = (float*)d_ws;

    wave_sim<<<BATCHD, 1024, 0, stream>>>(x, c, probes, partial);
    reduce_k<<<1, 64, 0, stream>>>(partial, out);
}